// Round 7
// baseline (4342.047 us; speedup 1.0000x reference)
//
#include <hip/hip_runtime.h>

typedef __attribute__((ext_vector_type(8))) __bf16 bf16x8;
typedef __attribute__((ext_vector_type(4))) float f32x4;

#define MFMA16(a, b, c) __builtin_amdgcn_mfma_f32_16x16x32_bf16(a, b, c, 0, 0, 0)

#define T_SEQ 512
#define F_IN 32
#define H1 128
#define E2 64
#define ROWS 4          // batch rows per block-pair
#define RING 16         // h1 ring slots (per pair): 16 * 2048B = 32KB; 128 pairs = 4MB

__device__ __forceinline__ float bf2f(ushort u) {
    union { uint i; float f; } v; v.i = ((uint)u) << 16; return v.f;
}
__device__ __forceinline__ ushort f2bf(float f) {
    union { float f; uint i; } v; v.f = f;
    uint r = v.i + 0x7fffu + ((v.i >> 16) & 1u);
    return (ushort)(r >> 16);
}
__device__ __forceinline__ float fast_sigmoid(float x) {
    float e = __expf(-x);
    return __builtin_amdgcn_rcpf(1.0f + e);
}
__device__ __forceinline__ float fast_tanh(float x) {
    float e = __expf(-2.0f * x);
    return 2.0f * __builtin_amdgcn_rcpf(1.0f + e) - 1.0f;
}
__device__ __forceinline__ bf16x8 load_w8(const float* p) {
    bf16x8 r;
#pragma unroll
    for (int j = 0; j < 8; ++j) r[j] = (__bf16)p[j];
    return r;
}

// ============================================================================
// PIPELINE kernels (r7): L1 (producer) and L2 (consumer) on DIFFERENT CUs.
// L2 never feeds back into L1 -> the only one-directional cut. Producer block
// 2b runs the h1 recurrence at 80 MFMA/SIMD/step (vs 128 fused); it streams
// h1(t) bf16 hi/lo through a RING-slot window in d_ws, released per-step via
// agent-scope release (post-barrier, off critical path). Consumer block 2b+1:
// waves 0-3 compute L2 (48 MFMA/wave) from LDS h1L; waves 4-7 prefetch
// h1(t+1) ring->LDS one step ahead (hides cross-XCD latency). Consumer trails
// ~8-15 steps, finishes ~1 step after producer. Flags zeroed by pipe_init on
// the same stream. Numerics bit-identical to the fused r6 kernel.
// ============================================================================

__global__ void pipe_init(uint* flags) {
    if (threadIdx.x < 256) flags[threadIdx.x] = 0;
}

__global__ __attribute__((amdgpu_flat_work_group_size(512, 512), amdgpu_waves_per_eu(2, 2)))
void lstm_pipe(
    const float* __restrict__ x,      // [512][512][32]
    const float* __restrict__ Wih1,   // [512][32]
    const float* __restrict__ Whh1,   // [512][128]
    const float* __restrict__ bih1,   // [512]
    const float* __restrict__ bhh1,   // [512]
    const float* __restrict__ Wih2,   // [256][128]
    const float* __restrict__ Whh2,   // [256][64]
    const float* __restrict__ bih2,   // [256]
    const float* __restrict__ bhh2,   // [256]
    float* __restrict__ out,          // [512][64] fp32
    ushort* __restrict__ ring,        // [128][RING][4][256] h1 hi/lo stream
    uint* __restrict__ flags)         // [0..127] producer, [128..255] consumer
{
    const int tid  = threadIdx.x;
    const int wave = tid >> 6;
    const int lane = tid & 63;
    const int l15  = lane & 15;
    const int quad = lane >> 4;
    const int arow = l15 >> 2;        // broadcast A-row (batch row)
    const int b    = blockIdx.x >> 1;
    const int r0   = b * ROWS;
    uint* const pflag = flags + b;
    uint* const cflag = flags + 128 + b;
    ushort* const myring = ring + (size_t)b * RING * 1024;

    if ((blockIdx.x & 1) == 0) {
        // ========================= PRODUCER (L1) =========================
        __shared__ __align__(16) ushort xs [16][ROWS][80];
        __shared__ __align__(16) ushort h1s[2][ROWS][272];

        bf16x8 wf[20];
        float  bias[4];
#pragma unroll
        for (int g = 0; g < 4; ++g) {
            const int n = g * 128 + wave * 16 + l15;
#pragma unroll
            for (int kt = 0; kt < 4; ++kt)
                wf[g * 4 + kt] = load_w8(Whh1 + n * H1 + kt * 32 + quad * 8);
            wf[16 + g] = load_w8(Wih1 + n * F_IN + quad * 8);
            bias[g] = bih1[n] + bhh1[n];
        }
        for (int i = tid; i < 2 * ROWS * 272; i += 512) ((ushort*)h1s)[i] = 0;

        float cst = 0.0f;

        // x staging: tid<128, batched ring (r6 scheme)
        const int xrow = (tid >> 5) & 3, xcol = tid & 31;
        const bool stager = (tid < 128);
        const float* xptr = x + ((size_t)(r0 + xrow) * T_SEQ) * F_IN + xcol;
        float xr8[8];
#pragma unroll
        for (int j = 0; j < 8; ++j) xr8[j] = 0.0f;
        if (stager) {
            float t0[8];
#pragma unroll
            for (int j = 0; j < 8; ++j) t0[j] = xptr[(size_t)j * F_IN];
#pragma unroll
            for (int j = 0; j < 8; ++j) {
                const ushort h = f2bf(t0[j]);
                xs[j][xrow][xcol]      = h;
                xs[j][xrow][32 + xcol] = f2bf(t0[j] - bf2f(h));
            }
#pragma unroll
            for (int j = 0; j < 8; ++j) xr8[j] = xptr[(size_t)(8 + j) * F_IN];
        }
        __syncthreads();

        f32x4 acc[4];
#pragma unroll 1
        for (int tt = 0; tt < T_SEQ; ++tt) {
            const int p = tt & 1, pn = p ^ 1;

            // ring throttle, once per 8 steps: need cons >= tt-8
            if ((tt & 7) == 0 && tt >= RING) {
                if (tid == 0) {
                    while (__hip_atomic_load(cflag, __ATOMIC_RELAXED,
                                             __HIP_MEMORY_SCOPE_AGENT) + 8u < (uint)tt) {}
                }
                __syncthreads();
            }

            // ---- L1 GEMM: 4 gates x 16 units, K = 64(x) + 256(h1) ----
#pragma unroll
            for (int g = 0; g < 4; ++g)
                acc[g] = (f32x4){bias[g], bias[g], bias[g], bias[g]};
            __builtin_amdgcn_s_setprio(1);
#pragma unroll
            for (int xt = 0; xt < 2; ++xt) {
                const bf16x8 ax = *(const bf16x8*)&xs[tt & 15][arow][xt * 32 + quad * 8];
#pragma unroll
                for (int g = 0; g < 4; ++g)
                    acc[g] = MFMA16(ax, wf[16 + g], acc[g]);
            }
#pragma unroll
            for (int kt = 0; kt < 8; ++kt) {
                const bf16x8 a = *(const bf16x8*)&h1s[p][arow][kt * 32 + quad * 8];
#pragma unroll
                for (int g = 0; g < 4; ++g)
                    acc[g] = MFMA16(a, wf[g * 4 + (kt & 3)], acc[g]);
            }
            __builtin_amdgcn_s_setprio(0);

            // ---- epilogue: 1 update/lane; write LDS feedback + global ring ----
            {
                const int u = wave * 16 + l15;
                const float iv = fast_sigmoid(acc[0][0]);
                const float fv = fast_sigmoid(acc[1][0]);
                const float gv = fast_tanh   (acc[2][0]);
                const float ov = fast_sigmoid(acc[3][0]);
                const float cn = fv * cst + iv * gv;
                cst = cn;
                const float h = ov * fast_tanh(cn);
                const ushort hi = f2bf(h);
                const ushort lo = f2bf(h - bf2f(hi));
                h1s[pn][quad][u]       = hi;
                h1s[pn][quad][128 + u] = lo;
                ushort* slot = myring + (size_t)(tt & (RING - 1)) * 1024;
                slot[quad * 256 + u]       = hi;
                slot[quad * 256 + 128 + u] = lo;
            }

            // ---- batched x staging, once per 8 steps ----
            if (stager && (tt & 7) == 0) {
#pragma unroll
                for (int j = 0; j < 8; ++j) {
                    const int t = tt + 8 + j;
                    if (t < T_SEQ) {
                        const ushort h = f2bf(xr8[j]);
                        xs[t & 15][xrow][xcol]      = h;
                        xs[t & 15][xrow][32 + xcol] = f2bf(xr8[j] - bf2f(h));
                    }
                }
#pragma unroll
                for (int j = 0; j < 8; ++j) {
                    const int t = tt + 16 + j;
                    if (t < T_SEQ) xr8[j] = xptr[(size_t)t * F_IN];
                }
            }
            __syncthreads();   // all stores (LDS + ring) issued & drained per-wave
            if (tid == 0)
                __hip_atomic_store(pflag, (uint)(tt + 1), __ATOMIC_RELEASE,
                                   __HIP_MEMORY_SCOPE_AGENT);
        }
    } else {
        // ========================= CONSUMER (L2) =========================
        __shared__ __align__(16) ushort h1L[2][ROWS][272];
        __shared__ __align__(16) ushort h2s[2][ROWS][144];

        const int w = wave & 3;
        bf16x8 wf[24];
        float  bias[4];
        if (wave < 4) {
#pragma unroll
            for (int g = 0; g < 4; ++g) {
                const int n = g * 64 + w * 16 + l15;
#pragma unroll
                for (int kt = 0; kt < 4; ++kt)
                    wf[g * 4 + kt] = load_w8(Wih2 + n * H1 + kt * 32 + quad * 8);
#pragma unroll
                for (int kc = 0; kc < 2; ++kc)
                    wf[16 + g * 2 + kc] = load_w8(Whh2 + n * E2 + kc * 32 + quad * 8);
                bias[g] = bih2[n] + bhh2[n];
            }
        }
        for (int i = tid; i < 2 * ROWS * 144; i += 512) ((ushort*)h2s)[i] = 0;

        float cst = 0.0f;

        // prologue: waves 4-7 prefetch h1(0) -> h1L[0]
        if (wave >= 4) {
            const int r = wave - 4;
            if (lane == 0) {
                while (__hip_atomic_load(pflag, __ATOMIC_ACQUIRE,
                                         __HIP_MEMORY_SCOPE_AGENT) < 1u) {}
            }
            asm volatile("" ::: "memory");
            const uint2 v = *(const uint2*)(myring + r * 256 + lane * 4);
            *(uint2*)&h1L[0][r][lane * 4] = v;
        }
        __syncthreads();

        f32x4 acc[4];
#pragma unroll 1
        for (int it = 0; it < T_SEQ; ++it) {
            const int p = it & 1, pn = p ^ 1;

            if (wave < 4) {
                // ---- L2 GEMM: 4 gates x 16 units, K = 256(h1) + 128(h2) ----
#pragma unroll
                for (int g = 0; g < 4; ++g)
                    acc[g] = (f32x4){bias[g], bias[g], bias[g], bias[g]};
                __builtin_amdgcn_s_setprio(1);
#pragma unroll
                for (int kt = 0; kt < 8; ++kt) {
                    const bf16x8 a = *(const bf16x8*)&h1L[p][arow][kt * 32 + quad * 8];
#pragma unroll
                    for (int g = 0; g < 4; ++g)
                        acc[g] = MFMA16(a, wf[g * 4 + (kt & 3)], acc[g]);
                }
#pragma unroll
                for (int kt = 0; kt < 4; ++kt) {
                    const bf16x8 a = *(const bf16x8*)&h2s[p][arow][kt * 32 + quad * 8];
#pragma unroll
                    for (int g = 0; g < 4; ++g)
                        acc[g] = MFMA16(a, wf[16 + g * 2 + (kt & 1)], acc[g]);
                }
                __builtin_amdgcn_s_setprio(0);
                // ---- epilogue ----
                const int u = w * 16 + l15;
                const float iv = fast_sigmoid(acc[0][0]);
                const float fv = fast_sigmoid(acc[1][0]);
                const float gv = fast_tanh   (acc[2][0]);
                const float ov = fast_sigmoid(acc[3][0]);
                const float cn = fv * cst + iv * gv;
                cst = cn;
                const float h = ov * fast_tanh(cn);
                if (it == T_SEQ - 1) {
                    out[(size_t)(r0 + quad) * E2 + u] = h;
                } else {
                    const ushort hi = f2bf(h);
                    h2s[pn][quad][u]      = hi;
                    h2s[pn][quad][64 + u] = f2bf(h - bf2f(hi));
                }
            } else {
                // ---- prefetch h1(it+1) ring -> h1L[pn] ----
                const int r = wave - 4;
                if (it + 1 < T_SEQ) {
                    if (lane == 0) {
                        while (__hip_atomic_load(pflag, __ATOMIC_ACQUIRE,
                                                 __HIP_MEMORY_SCOPE_AGENT) < (uint)(it + 2)) {}
                    }
                    asm volatile("" ::: "memory");
                    const uint2 v = *(const uint2*)(myring +
                        (size_t)((it + 1) & (RING - 1)) * 1024 + r * 256 + lane * 4);
                    *(uint2*)&h1L[pn][r][lane * 4] = v;
                }
                if (wave == 4 && lane == 0 && (it & 7) == 7)
                    __hip_atomic_store(cflag, (uint)(it + 1), __ATOMIC_RELAXED,
                                       __HIP_MEMORY_SCOPE_AGENT);
            }
            __syncthreads();
        }
    }
}

// ============================================================================
// FALLBACK: r6 fused kernel verbatim (used when ws_size is too small).
// ============================================================================
__global__ __launch_bounds__(512, 1) void lstm_fused_fb(
    const float* __restrict__ x, const float* __restrict__ Wih1,
    const float* __restrict__ Whh1, const float* __restrict__ bih1,
    const float* __restrict__ bhh1, const float* __restrict__ Wih2,
    const float* __restrict__ Whh2, const float* __restrict__ bih2,
    const float* __restrict__ bhh2, float* __restrict__ out)
{
    __shared__ __align__(16) ushort xs [16][ROWS][80];
    __shared__ __align__(16) ushort h1s[2][ROWS][272];
    __shared__ __align__(16) ushort h2s[2][ROWS][144];

    const int tid  = threadIdx.x;
    const int wave = tid >> 6;
    const int lane = tid & 63;
    const int l15  = lane & 15;
    const int quad = lane >> 4;
    const int arow = l15 >> 2;
    const int r0   = blockIdx.x * ROWS;
    const bool isL1 = (wave < 4);
    const int w    = wave & 3;

    bf16x8 wf[40];
    float  bias[8];

    if (isL1) {
#pragma unroll
        for (int g = 0; g < 4; ++g)
#pragma unroll
            for (int uo = 0; uo < 2; ++uo) {
                const int tau = g * 2 + uo;
                const int n = g * 128 + w * 32 + uo * 16 + l15;
#pragma unroll
                for (int kt = 0; kt < 4; ++kt)
                    wf[tau * 4 + kt] = load_w8(Whh1 + n * H1 + kt * 32 + quad * 8);
                wf[32 + tau] = load_w8(Wih1 + n * F_IN + quad * 8);
                bias[tau] = bih1[n] + bhh1[n];
            }
    } else {
#pragma unroll
        for (int g = 0; g < 4; ++g) {
            const int n = g * 64 + w * 16 + l15;
#pragma unroll
            for (int kt = 0; kt < 4; ++kt)
                wf[g * 4 + kt] = load_w8(Wih2 + n * H1 + kt * 32 + quad * 8);
#pragma unroll
            for (int kc = 0; kc < 2; ++kc)
                wf[16 + g * 2 + kc] = load_w8(Whh2 + n * E2 + kc * 32 + quad * 8);
            bias[g] = bih2[n] + bhh2[n];
        }
    }

    for (int i = tid; i < 2 * ROWS * 272; i += 512) ((ushort*)h1s)[i] = 0;
    for (int i = tid; i < 2 * ROWS * 144; i += 512) ((ushort*)h2s)[i] = 0;

    float cst[2] = {0.0f, 0.0f};

    const int xrow = w;
    const int xcol = lane;
    const bool stager = (!isL1) && (lane < 32);
    const float* xptr = x + ((size_t)(r0 + xrow) * T_SEQ) * F_IN + xcol;
    float xr8[8];
#pragma unroll
    for (int j = 0; j < 8; ++j) xr8[j] = 0.0f;
    if (stager) {
        float t0[8];
#pragma unroll
        for (int j = 0; j < 8; ++j) t0[j] = xptr[(size_t)j * F_IN];
#pragma unroll
        for (int j = 0; j < 8; ++j) {
            const ushort h = f2bf(t0[j]);
            xs[j][xrow][xcol]      = h;
            xs[j][xrow][32 + xcol] = f2bf(t0[j] - bf2f(h));
        }
#pragma unroll
        for (int j = 0; j < 8; ++j) xr8[j] = xptr[(size_t)(8 + j) * F_IN];
    }
    __syncthreads();

    f32x4 acc[8];

#pragma unroll 1
    for (int tt = 0; tt <= T_SEQ; ++tt) {
        const int p  = tt & 1;
        const int pn = p ^ 1;

        if (isL1) {
            if (tt < T_SEQ) {
#pragma unroll
                for (int tau = 0; tau < 8; ++tau)
                    acc[tau] = (f32x4){bias[tau], bias[tau], bias[tau], bias[tau]};
                __builtin_amdgcn_s_setprio(1);
#pragma unroll
                for (int xt = 0; xt < 2; ++xt) {
                    const bf16x8 ax = *(const bf16x8*)&xs[tt & 15][arow][xt * 32 + quad * 8];
#pragma unroll
                    for (int tau = 0; tau < 8; ++tau)
                        acc[tau] = MFMA16(ax, wf[32 + tau], acc[tau]);
                }
#pragma unroll
                for (int kt = 0; kt < 8; ++kt) {
                    const bf16x8 a = *(const bf16x8*)&h1s[p][arow][kt * 32 + quad * 8];
#pragma unroll
                    for (int tau = 0; tau < 8; ++tau)
                        acc[tau] = MFMA16(a, wf[tau * 4 + (kt & 3)], acc[tau]);
                }
                __builtin_amdgcn_s_setprio(0);
#pragma unroll
                for (int uo = 0; uo < 2; ++uo) {
                    const int u = w * 32 + uo * 16 + l15;
                    const float iv = fast_sigmoid(acc[0 + uo][0]);
                    const float fv = fast_sigmoid(acc[2 + uo][0]);
                    const float gv = fast_tanh   (acc[4 + uo][0]);
                    const float ov = fast_sigmoid(acc[6 + uo][0]);
                    const float cn = fv * cst[uo] + iv * gv;
                    cst[uo] = cn;
                    const float h = ov * fast_tanh(cn);
                    const ushort hi = f2bf(h);
                    h1s[pn][quad][u]       = hi;
                    h1s[pn][quad][128 + u] = f2bf(h - bf2f(hi));
                }
            }
        } else {
            if (tt >= 1) {
#pragma unroll
                for (int g = 0; g < 4; ++g)
                    acc[g] = (f32x4){bias[g], bias[g], bias[g], bias[g]};
                __builtin_amdgcn_s_setprio(1);
#pragma unroll
                for (int kt = 0; kt < 8; ++kt) {
                    const bf16x8 a = *(const bf16x8*)&h1s[p][arow][kt * 32 + quad * 8];
#pragma unroll
                    for (int g = 0; g < 4; ++g)
                        acc[g] = MFMA16(a, wf[g * 4 + (kt & 3)], acc[g]);
                }
#pragma unroll
                for (int kt = 0; kt < 4; ++kt) {
                    const bf16x8 a = *(const bf16x8*)&h2s[p][arow][kt * 32 + quad * 8];
#pragma unroll
                    for (int g = 0; g < 4; ++g)
                        acc[g] = MFMA16(a, wf[16 + g * 2 + (kt & 1)], acc[g]);
                }
                __builtin_amdgcn_s_setprio(0);
                const int u = w * 16 + l15;
                const float iv = fast_sigmoid(acc[0][0]);
                const float fv = fast_sigmoid(acc[1][0]);
                const float gv = fast_tanh   (acc[2][0]);
                const float ov = fast_sigmoid(acc[3][0]);
                const float cn = fv * cst[0] + iv * gv;
                cst[0] = cn;
                const float h = ov * fast_tanh(cn);
                if (tt == T_SEQ) {
                    out[(size_t)(r0 + quad) * E2 + u] = h;
                } else {
                    const ushort hi = f2bf(h);
                    h2s[pn][quad][u]      = hi;
                    h2s[pn][quad][64 + u] = f2bf(h - bf2f(hi));
                }
            }
            if (stager && (tt & 7) == 0) {
#pragma unroll
                for (int j = 0; j < 8; ++j) {
                    const int t = tt + 8 + j;
                    if (t < T_SEQ) {
                        const ushort h = f2bf(xr8[j]);
                        xs[t & 15][xrow][xcol]      = h;
                        xs[t & 15][xrow][32 + xcol] = f2bf(xr8[j] - bf2f(h));
                    }
                }
#pragma unroll
                for (int j = 0; j < 8; ++j) {
                    const int t = tt + 16 + j;
                    if (t < T_SEQ) xr8[j] = xptr[(size_t)t * F_IN];
                }
            }
        }
        __syncthreads();
    }
}

extern "C" void kernel_launch(void* const* d_in, const int* in_sizes, int n_in,
                              void* d_out, int out_size, void* d_ws, size_t ws_size,
                              hipStream_t stream) {
    const size_t ring_bytes = (size_t)128 * RING * 1024 * sizeof(ushort);  // 4 MiB
    const size_t needed = ring_bytes + 256 * sizeof(uint);
    if (d_ws != nullptr && ws_size >= needed) {
        ushort* ring = (ushort*)d_ws;
        uint* flags = (uint*)((char*)d_ws + ring_bytes);
        pipe_init<<<1, 256, 0, stream>>>(flags);
        lstm_pipe<<<256, 512, 0, stream>>>(
            (const float*)d_in[0], (const float*)d_in[1], (const float*)d_in[2],
            (const float*)d_in[3], (const float*)d_in[4], (const float*)d_in[5],
            (const float*)d_in[6], (const float*)d_in[7], (const float*)d_in[8],
            (float*)d_out, ring, flags);
    } else {
        lstm_fused_fb<<<128, 512, 0, stream>>>(
            (const float*)d_in[0], (const float*)d_in[1], (const float*)d_in[2],
            (const float*)d_in[3], (const float*)d_in[4], (const float*)d_in[5],
            (const float*)d_in[6], (const float*)d_in[7], (const float*)d_in[8],
            (float*)d_out);
    }
}

// Round 8
// 475.350 us; speedup vs baseline: 9.1344x; 9.1344x over previous
//
#include <hip/hip_runtime.h>

typedef __attribute__((ext_vector_type(8))) _Float16 halfx8;
typedef __attribute__((ext_vector_type(4))) float f32x4;

#define MFMA16H(a, b, c) __builtin_amdgcn_mfma_f32_16x16x32_f16(a, b, c, 0, 0, 0)

#define T_SEQ 512
#define F_IN 32
#define H1 128
#define E2 64
#define ROWS 4          // batch rows per block

__device__ __forceinline__ ushort f2h(float f) {
    _Float16 h = (_Float16)f;              // v_cvt_f16_f32, RNE
    return __builtin_bit_cast(ushort, h);
}
__device__ __forceinline__ float fast_sigmoid(float x) {
    float e = __expf(-x);
    return __builtin_amdgcn_rcpf(1.0f + e);
}
__device__ __forceinline__ float fast_tanh(float x) {
    float e = __expf(-2.0f * x);
    return 2.0f * __builtin_amdgcn_rcpf(1.0f + e) - 1.0f;
}
__device__ __forceinline__ halfx8 load_w8h(const float* p) {
    halfx8 r;
#pragma unroll
    for (int j = 0; j < 8; ++j) r[j] = (_Float16)p[j];
    return r;
}

// Fused 2-layer LSTM, 128 blocks x 512 threads (8 waves), 4 batch rows/blk.
//
// ROUND THEORY (halve K via fp16): occupancy counters are device-wide over a
// half-idle chip (128 blocks / 256 CUs) -> active-CU MfmaUtil ~64%: the step
// is MFMA-issue-bound, which is why r4/r5/r6 scheduling changes were all
// within noise at 722us. The MFMA stream is 2x inflated by the bf16 hi/lo
// activation scheme - while WEIGHTS are single bf16 (2^-9 rel error) and
// dominate absmax (2^-10 observed). fp16 fits every value range here
// (h in (-1,1), x ~ N(0,1), w ~ +-0.09, gates bounded): weights 2^-9->2^-12
// (absmax should improve), activations 2^-16->2^-12 (still sub-dominant).
// MFMA/SIMD/step: 128 -> 64 (L1 wave 80->40, L2 48->24); staging/epilogue
// lose all lo-computation VALU. Everything else identical to r6: same wave
// mapping, same conflict-free strides (== 16 mod 64 ushorts), batched x
// staging, setprio.
__global__ __launch_bounds__(512, 1) void lstm_fused(
    const float* __restrict__ x,      // [512][512][32]
    const float* __restrict__ Wih1,   // [512][32]
    const float* __restrict__ Whh1,   // [512][128]
    const float* __restrict__ bih1,   // [512]
    const float* __restrict__ bhh1,   // [512]
    const float* __restrict__ Wih2,   // [256][128]
    const float* __restrict__ Whh2,   // [256][64]
    const float* __restrict__ bih2,   // [256]
    const float* __restrict__ bhh2,   // [256]
    float* __restrict__ out)          // [512][64] fp32
{
    __shared__ __align__(16) ushort xs [16][ROWS][80];  // fp16 x(t) ring, cols 0..31
    __shared__ __align__(16) ushort h1s[2][ROWS][144];  // fp16 h1, cols 0..127
    __shared__ __align__(16) ushort h2s[2][ROWS][80];   // fp16 h2, cols 0..63

    const int tid  = threadIdx.x;
    const int wave = tid >> 6;
    const int lane = tid & 63;
    const int l15  = lane & 15;
    const int quad = lane >> 4;
    const int arow = l15 >> 2;        // broadcast A-row (batch row) for ds_reads
    const int r0   = blockIdx.x * ROWS;
    const bool isL1 = (wave < 4);
    const int w    = wave & 3;

    // Weight fragment file (disjoint per wave group), fp16:
    //  L1 (tau = g*2+uo): wf[tau*4+kt] = Whh1 frag (K=128, 32 frags),
    //                     wf[32+tau]   = Wih1 frag (K=32, 8 frags)
    //  L2 (g):            wf[g*4+kt]   = Wih2 frag (K=128, 16 frags),
    //                     wf[16+g*2+kc]= Whh2 frag (K=64, 8 frags)
    halfx8 wf[40];
    float  bias[8];

    if (isL1) {
#pragma unroll
        for (int g = 0; g < 4; ++g)
#pragma unroll
            for (int uo = 0; uo < 2; ++uo) {
                const int tau = g * 2 + uo;
                const int n = g * 128 + w * 32 + uo * 16 + l15;
#pragma unroll
                for (int kt = 0; kt < 4; ++kt)
                    wf[tau * 4 + kt] = load_w8h(Whh1 + n * H1 + kt * 32 + quad * 8);
                wf[32 + tau] = load_w8h(Wih1 + n * F_IN + quad * 8);
                bias[tau] = bih1[n] + bhh1[n];
            }
    } else {
#pragma unroll
        for (int g = 0; g < 4; ++g) {
            const int n = g * 64 + w * 16 + l15;
#pragma unroll
            for (int kt = 0; kt < 4; ++kt)
                wf[g * 4 + kt] = load_w8h(Wih2 + n * H1 + kt * 32 + quad * 8);
#pragma unroll
            for (int kc = 0; kc < 2; ++kc)
                wf[16 + g * 2 + kc] = load_w8h(Whh2 + n * E2 + kc * 32 + quad * 8);
            bias[g] = bih2[n] + bhh2[n];
        }
    }

    // zero both h-state buffers (fp16 zero == 0 bits)
    for (int i = tid; i < 2 * ROWS * 144; i += 512) ((ushort*)h1s)[i] = 0;
    for (int i = tid; i < 2 * ROWS * 80;  i += 512) ((ushort*)h2s)[i] = 0;

    // cell states: lane (quad,l15) owns batch row 'quad'
    float cst[2] = {0.0f, 0.0f};      // L1: per uo; L2 uses cst[0]

    // x staging: 32 lanes of each L2 wave; wave 4+xr stages batch row xr.
    const int xrow = w;               // for L2 waves
    const int xcol = lane;            // 0..31 valid
    const bool stager = (!isL1) && (lane < 32);
    const float* xptr = x + ((size_t)(r0 + xrow) * T_SEQ) * F_IN + xcol;
    float xr8[8];
#pragma unroll
    for (int j = 0; j < 8; ++j) xr8[j] = 0.0f;
    if (stager) {
        // prologue: stage t=0..7 into slots 0..7, prefetch t=8..15 into regs
        float t0[8];
#pragma unroll
        for (int j = 0; j < 8; ++j) t0[j] = xptr[(size_t)j * F_IN];
#pragma unroll
        for (int j = 0; j < 8; ++j) xs[j][xrow][xcol] = f2h(t0[j]);
#pragma unroll
        for (int j = 0; j < 8; ++j) xr8[j] = xptr[(size_t)(8 + j) * F_IN];
    }
    __syncthreads();

    f32x4 acc[8];

#pragma unroll 1
    for (int tt = 0; tt <= T_SEQ; ++tt) {
        const int p  = tt & 1;
        const int pn = p ^ 1;

        if (isL1) {
            if (tt < T_SEQ) {
                // ---- L1 GEMM: 4 gates x 32 units, K = 32(x) + 128(h1) ----
#pragma unroll
                for (int tau = 0; tau < 8; ++tau)
                    acc[tau] = (f32x4){bias[tau], bias[tau], bias[tau], bias[tau]};
                __builtin_amdgcn_s_setprio(1);
                {
                    const halfx8 ax = *(const halfx8*)&xs[tt & 15][arow][quad * 8];
#pragma unroll
                    for (int tau = 0; tau < 8; ++tau)
                        acc[tau] = MFMA16H(ax, wf[32 + tau], acc[tau]);
                }
#pragma unroll
                for (int kt = 0; kt < 4; ++kt) {
                    const halfx8 a = *(const halfx8*)&h1s[p][arow][kt * 32 + quad * 8];
#pragma unroll
                    for (int tau = 0; tau < 8; ++tau)
                        acc[tau] = MFMA16H(a, wf[tau * 4 + kt], acc[tau]);
                }
                __builtin_amdgcn_s_setprio(0);
                // ---- L1 epilogue, in-register, all 64 lanes ----
#pragma unroll
                for (int uo = 0; uo < 2; ++uo) {
                    const int u = w * 32 + uo * 16 + l15;
                    const float iv = fast_sigmoid(acc[0 + uo][0]);
                    const float fv = fast_sigmoid(acc[2 + uo][0]);
                    const float gv = fast_tanh   (acc[4 + uo][0]);
                    const float ov = fast_sigmoid(acc[6 + uo][0]);
                    const float cn = fv * cst[uo] + iv * gv;
                    cst[uo] = cn;
                    const float h = ov * fast_tanh(cn);
                    h1s[pn][quad][u] = f2h(h);
                }
            }
        } else {
            if (tt >= 1) {
                // ---- L2 GEMM: 4 gates x 16 units, K = 128(h1) + 64(h2) ----
#pragma unroll
                for (int g = 0; g < 4; ++g)
                    acc[g] = (f32x4){bias[g], bias[g], bias[g], bias[g]};
                __builtin_amdgcn_s_setprio(1);
#pragma unroll
                for (int kt = 0; kt < 4; ++kt) {
                    const halfx8 a = *(const halfx8*)&h1s[p][arow][kt * 32 + quad * 8];
#pragma unroll
                    for (int g = 0; g < 4; ++g)
                        acc[g] = MFMA16H(a, wf[g * 4 + kt], acc[g]);
                }
#pragma unroll
                for (int kc = 0; kc < 2; ++kc) {
                    const halfx8 a = *(const halfx8*)&h2s[p][arow][kc * 32 + quad * 8];
#pragma unroll
                    for (int g = 0; g < 4; ++g)
                        acc[g] = MFMA16H(a, wf[16 + g * 2 + kc], acc[g]);
                }
                __builtin_amdgcn_s_setprio(0);
                // ---- L2 epilogue, in-register, all 64 lanes ----
                const int u = w * 16 + l15;
                const float iv = fast_sigmoid(acc[0][0]);
                const float fv = fast_sigmoid(acc[1][0]);
                const float gv = fast_tanh   (acc[2][0]);
                const float ov = fast_sigmoid(acc[3][0]);
                const float cn = fv * cst[0] + iv * gv;
                cst[0] = cn;
                const float h = ov * fast_tanh(cn);
                if (tt == T_SEQ) {
                    out[(size_t)(r0 + quad) * E2 + u] = h;
                } else {
                    h2s[pn][quad][u] = f2h(h);
                }
            }
            // ---- batched x staging, once every 8 steps ----
            if (stager && (tt & 7) == 0) {
#pragma unroll
                for (int j = 0; j < 8; ++j) {
                    const int t = tt + 8 + j;
                    if (t < T_SEQ) xs[t & 15][xrow][xcol] = f2h(xr8[j]);
                }
#pragma unroll
                for (int j = 0; j < 8; ++j) {
                    const int t = tt + 16 + j;
                    if (t < T_SEQ) xr8[j] = xptr[(size_t)t * F_IN];
                }
            }
        }
        __syncthreads();   // single barrier: buf pn complete, buf p reads done
    }
}

extern "C" void kernel_launch(void* const* d_in, const int* in_sizes, int n_in,
                              void* d_out, int out_size, void* d_ws, size_t ws_size,
                              hipStream_t stream) {
    lstm_fused<<<128, 512, 0, stream>>>(
        (const float*)d_in[0], (const float*)d_in[1], (const float*)d_in[2],
        (const float*)d_in[3], (const float*)d_in[4], (const float*)d_in[5],
        (const float*)d_in[6], (const float*)d_in[7], (const float*)d_in[8],
        (float*)d_out);
}